// Round 5
// baseline (75.268 us; speedup 1.0000x reference)
//
#include <hip/hip_runtime.h>
#include <hip/hip_bf16.h>
#include <stdint.h>

// Problem constants: B=4, N=4096, C=1024, H=16, d=64
typedef __attribute__((ext_vector_type(8))) short bf16x8;
typedef __attribute__((ext_vector_type(4))) short bf16x4;
typedef __attribute__((ext_vector_type(4))) float f32x4;
typedef __attribute__((ext_vector_type(4))) int   i32x4;

static __device__ __forceinline__ short f2bs(float f) {
  __hip_bfloat16 h = __float2bfloat16(f);
  return __builtin_bit_cast(short, h);
}

__device__ __forceinline__ void gload_lds16(const void* g, void* l) {
  auto* gp = reinterpret_cast<__attribute__((address_space(1))) uint32_t*>((uintptr_t)g);
  auto* lp = reinterpret_cast<__attribute__((address_space(3))) uint32_t*>((uintptr_t)l);
  __builtin_amdgcn_global_load_lds(gp, lp, 16, 0, 0);
}

// ---------------------------------------------------------------------------
// Kernel 1: per-token head-mix attention, fully in registers via MFMA.
// (unchanged — isolating the GEMM change this round)
// ---------------------------------------------------------------------------
__global__ __launch_bounds__(256) void attn_kernel(
    const float* __restrict__ x, const float* __restrict__ y,
    __hip_bfloat16* __restrict__ A)
{
  const int wid  = threadIdx.x >> 6;
  const int lane = threadIdx.x & 63;
  const int tok  = blockIdx.x * 4 + wid;        // 0..16383
  const int b    = tok >> 12;
  const int n    = tok & 4095;

  const float* xr = x + (size_t)tok * 1024;
  const float* yr = y + (size_t)tok * 1024;

  const int c  = lane & 15;
  const int qq = lane >> 4;

  const int fbase = c * 64 + qq * 8;
  bf16x8 yf[2], xf[2];
  #pragma unroll
  for (int kk = 0; kk < 2; ++kk) {
    const float4 a0 = *(const float4*)(yr + fbase + kk * 32);
    const float4 a1 = *(const float4*)(yr + fbase + kk * 32 + 4);
    const float4 b0 = *(const float4*)(xr + fbase + kk * 32);
    const float4 b1 = *(const float4*)(xr + fbase + kk * 32 + 4);
    yf[kk] = bf16x8{f2bs(a0.x), f2bs(a0.y), f2bs(a0.z), f2bs(a0.w),
                    f2bs(a1.x), f2bs(a1.y), f2bs(a1.z), f2bs(a1.w)};
    xf[kk] = bf16x8{f2bs(b0.x), f2bs(b0.y), f2bs(b0.z), f2bs(b0.w),
                    f2bs(b1.x), f2bs(b1.y), f2bs(b1.z), f2bs(b1.w)};
  }

  f32x4 acc = {0.f, 0.f, 0.f, 0.f};
  acc = __builtin_amdgcn_mfma_f32_16x16x32_bf16(yf[0], xf[0], acc, 0, 0, 0);
  acc = __builtin_amdgcn_mfma_f32_16x16x32_bf16(yf[1], xf[1], acc, 0, 0, 0);

  float sc[4];
  #pragma unroll
  for (int r = 0; r < 4; ++r) sc[r] = acc[r] * 0.125f;
  float mx = fmaxf(fmaxf(sc[0], sc[1]), fmaxf(sc[2], sc[3]));
  mx = fmaxf(mx, __shfl_xor(mx, 16));
  mx = fmaxf(mx, __shfl_xor(mx, 32));
  float e[4];
  #pragma unroll
  for (int r = 0; r < 4; ++r) e[r] = __expf(sc[r] - mx);
  float sm = (e[0] + e[1]) + (e[2] + e[3]);
  sm += __shfl_xor(sm, 16);
  sm += __shfl_xor(sm, 32);
  const float inv = 1.0f / sm;
  float p[4];
  #pragma unroll
  for (int r = 0; r < 4; ++r) p[r] = e[r] * inv;

  f32x4 o[4];
  #pragma unroll
  for (int q = 0; q < 4; ++q) o[q] = f32x4{0.f, 0.f, 0.f, 0.f};

#if __has_builtin(__builtin_amdgcn_mfma_f32_16x16x16bf16_1k)
  const bf16x4 pa = {f2bs(p[0]), f2bs(p[1]), f2bs(p[2]), f2bs(p[3])};
  #pragma unroll
  for (int q = 0; q < 4; ++q) {
    bf16x4 bq;
    #pragma unroll
    for (int j = 0; j < 4; ++j)
      bq[j] = f2bs(yr[(qq * 4 + j) * 64 + q * 16 + c]);
    o[q] = __builtin_amdgcn_mfma_f32_16x16x16bf16_1k(pa, bq, o[q], 0, 0, 0);
  }
#else
  const int u0 = ((int)(unsigned short)f2bs(p[1]) << 16) | (unsigned short)f2bs(p[0]);
  const int u1 = ((int)(unsigned short)f2bs(p[3]) << 16) | (unsigned short)f2bs(p[2]);
  const int s0 = c + 32 * qq;
  int a0 = __shfl(u0, s0), a1 = __shfl(u1, s0);
  int a2 = __shfl(u0, s0 + 16), a3 = __shfl(u1, s0 + 16);
  const bool valid = (qq < 2);
  if (!valid) { a0 = 0; a1 = 0; a2 = 0; a3 = 0; }
  const bf16x8 a8 = __builtin_bit_cast(bf16x8, i32x4{a0, a1, a2, a3});
  #pragma unroll
  for (int q = 0; q < 4; ++q) {
    bf16x8 b8;
    #pragma unroll
    for (int j = 0; j < 8; ++j) {
      const int g = (qq * 8 + j) & 15;
      const float v = yr[g * 64 + q * 16 + c];
      b8[j] = valid ? f2bs(v) : (short)0;
    }
    o[q] = __builtin_amdgcn_mfma_f32_16x16x32_bf16(a8, b8, o[q], 0, 0, 0);
  }
#endif

  const size_t base = ((size_t)b * 4096 + (n >> 4)) * 1024 + ((n & 15) << 6) + c;
  #pragma unroll
  for (int q = 0; q < 4; ++q)
    #pragma unroll
    for (int r = 0; r < 4; ++r) {
      const int h = qq * 4 + r;
      A[base + (size_t)h * 262144 + q * 16] = __float2bfloat16(o[q][r]);
    }
}

// ---------------------------------------------------------------------------
// Kernel 2: W fp32 -> bf16
// ---------------------------------------------------------------------------
__global__ __launch_bounds__(256) void wcvt_kernel(const float* __restrict__ w,
                                                   __hip_bfloat16* __restrict__ wb)
{
  const int i = (blockIdx.x * 256 + threadIdx.x) * 4;
  const float4 v = *(const float4*)(w + i);
  wb[i + 0] = __float2bfloat16(v.x);
  wb[i + 1] = __float2bfloat16(v.y);
  wb[i + 2] = __float2bfloat16(v.z);
  wb[i + 3] = __float2bfloat16(v.w);
}

// ---------------------------------------------------------------------------
// Kernel 3: out[M,Nn] = A[M,K] * Bw[Nn,K]^T + bias, fp32 out.
// 256x256 tile, BK=64, 8 waves (2M x 4N), 128 KiB dbuf LDS.
// m201-style 4-phase/K-tile schedule with COUNTED vmcnt (never 0 in loop):
//   stage order per tile: ph1 {B0,B1} ph2 {B2,B3} ph3 {A0,A2} ph4 {A1,A3}
//   gates: vmcnt(2) end-ph1 (A-bands 1,3 of current tile)
//          vmcnt(2) end-ph4 (B-all + A-bands 0,2 of next tile)
// T2 both-sides XOR swizzle, T5 setprio, T1 bijective XCD chunking.
// Last tile peeled: early C-store of acc[0-3] overlaps phase 4.
// ---------------------------------------------------------------------------
#define NT 16   // K / 64

#define FENCE asm volatile("" ::: "memory")
#define BAR   __builtin_amdgcn_s_barrier()
#define LGKM0 asm volatile("s_waitcnt lgkmcnt(0)" ::: "memory")
#define VM2   asm volatile("s_waitcnt vmcnt(2)" ::: "memory")
#define VM0   asm volatile("s_waitcnt vmcnt(0)" ::: "memory")
#define SB0   __builtin_amdgcn_sched_barrier(0)
#define SP1   __builtin_amdgcn_s_setprio(1)
#define SP0   __builtin_amdgcn_s_setprio(0)

// band j covers tile rows j*64..j*64+63 (8 KB of LDS, 2 gload instrs... 1 instr)
#define SGA(j, toff, bufn) gload_lds16(aSrc + (toff) + (j) * 131072, aDst + (bufn) * 32768 + (j) * 8192)
#define SGB(j, toff, bufn) gload_lds16(bSrc + (toff) + (j) * 131072, bDst + (bufn) * 32768 + (j) * 8192)

#define MFMA16(MO)                                                         \
  _Pragma("unroll")                                                        \
  for (int m = 0; m < 4; ++m)                                              \
    _Pragma("unroll")                                                      \
    for (int n = 0; n < 4; ++n)                                            \
      acc[(MO) + m][n] = __builtin_amdgcn_mfma_f32_16x16x32_bf16(Af[m], Bf[n], acc[(MO) + m][n], 0, 0, 0)

#define READ_B(OF)                                                         \
  _Pragma("unroll")                                                        \
  for (int n = 0; n < 4; ++n) Bf[n] = *(const bf16x8*)(bR + n * 2048 + (OF))

#define READ_A(MO, OF)                                                     \
  _Pragma("unroll")                                                        \
  for (int m = 0; m < 4; ++m) Af[m] = *(const bf16x8*)(aR + ((MO) + m) * 2048 + (OF))

__global__ __launch_bounds__(512, 2) void gemm256(
    const __hip_bfloat16* __restrict__ A,   // [M,K] row-major bf16
    const __hip_bfloat16* __restrict__ Bw,  // [Nn,K] row-major bf16 (= W^T layout)
    const float* __restrict__ bias,         // [Nn]
    float* __restrict__ C)                  // [M,Nn] fp32
{
  constexpr int K = 1024, Nn = 1024;
  __shared__ char ldsA[2 * 32768];          // [buf][256 rows][128B], swizzled
  __shared__ char ldsB[2 * 32768];

  const int tid  = threadIdx.x;             // 0..511
  const int lane = tid & 63;
  const int wid  = tid >> 6;                // 8 waves
  const int wr   = wid >> 2;                // 0..1  (M half: 128 rows)
  const int wc   = wid & 3;                 // 0..3  (N quarter: 64 cols)

  // XCD-chunked bijective swizzle: 256 blocks = 8 XCDs x 32 contiguous tiles.
  const int bid = blockIdx.x;
  const int nb  = (bid & 7) * 32 + (bid >> 3);
  const int mBase = (nb >> 2) * 256;        // 64 M-tiles
  const int nBase = (nb & 3) * 256;         // 4 N-tiles

  // ---- staging geometry: linear LDS dest, pre-swizzled global source ----
  const int srow = tid >> 3;                // row within 64-row band
  const int lcb  = ((tid & 7) << 4) ^ ((srow & 7) << 4);
  const char* aSrc = (const char*)A  + ((size_t)(mBase + srow) * K) * 2 + lcb;
  const char* bSrc = (const char*)Bw + ((size_t)(nBase + srow) * K) * 2 + lcb;
  char* aDst = ldsA + tid * 16;
  char* bDst = ldsB + tid * 16;

  // ---- ds_read geometry (swizzled) ----
  const int fr = lane & 15;                 // fragment row
  const int kq = lane >> 4;                 // k-quad
  const int xr = (fr & 7) << 4;
  const int ofk0 = ((kq << 4))      ^ xr;   // k-half 0 colbyte
  const int ofk1 = (64 + (kq << 4)) ^ xr;   // k-half 1 colbyte
  const char* aRow = ldsA + (wr * 128 + fr) * 128;
  const char* bRow = ldsB + (wc * 64  + fr) * 128;

  f32x4 acc[8][4];
  #pragma unroll
  for (int m = 0; m < 8; ++m)
    #pragma unroll
    for (int n = 0; n < 4; ++n) acc[m][n] = f32x4{0.f, 0.f, 0.f, 0.f};

  // ---- prologue: stage tile 0 in read-order {B0..B3, A0, A2, A1, A3} ----
  SGB(0, 0, 0); SGB(1, 0, 0); SGB(2, 0, 0); SGB(3, 0, 0);
  SGA(0, 0, 0); SGA(2, 0, 0); SGA(1, 0, 0); SGA(3, 0, 0);
  VM2;                                      // first 6 (B all + A0,A2) landed
  BAR;

  // ---- main loop: tiles 0..NT-2, staging tile t+1 ----
  for (int t = 0; t < NT - 1; ++t) {
    const int cur  = t & 1;
    const int nxt  = cur ^ 1;
    const int toff = (t + 1) * 128;
    const char* aR = aRow + cur * 32768;
    const char* bR = bRow + cur * 32768;
    bf16x8 Af[4], Bf[4];

    // ph1: kh0, m0-3 | stage B0,B1(t+1) | gate A1,A3(t) at end
    SGB(0, toff, nxt); SGB(1, toff, nxt);
    READ_B(ofk0); READ_A(0, ofk0);
    FENCE; BAR; LGKM0; SB0;
    SP1; MFMA16(0); SP0;
    VM2; FENCE; BAR;

    // ph2: kh0, m4-7 (reuse Bf) | stage B2,B3(t+1)
    SGB(2, toff, nxt); SGB(3, toff, nxt);
    READ_A(4, ofk0);
    FENCE; BAR; LGKM0; SB0;
    SP1; MFMA16(4); SP0;
    FENCE; BAR;

    // ph3: kh1, m0-3 | stage A0,A2(t+1)
    SGA(0, toff, nxt); SGA(2, toff, nxt);
    READ_B(ofk1); READ_A(0, ofk1);
    FENCE; BAR; LGKM0; SB0;
    SP1; MFMA16(0); SP0;
    FENCE; BAR;

    // ph4: kh1, m4-7 | stage A1,A3(t+1) | gate B0-3+A0,A2(t+1) at end
    SGA(1, toff, nxt); SGA(3, toff, nxt);
    READ_A(4, ofk1);
    FENCE; BAR; LGKM0; SB0;
    SP1; MFMA16(4); SP0;
    VM2; FENCE; BAR;
  }

  // ---- peeled last tile (no staging); early C-store of acc[0-3] ----
  const int fq = lane >> 4;
  {
    const char* aR = aRow + ((NT - 1) & 1) * 32768;
    const char* bR = bRow + ((NT - 1) & 1) * 32768;
    bf16x8 Af[4], Bf[4];

    // ph1
    READ_B(ofk0); READ_A(0, ofk0);
    FENCE; BAR; LGKM0; SB0;
    SP1; MFMA16(0); SP0;
    VM0; FENCE; BAR;                        // ensure A1,A3 landed (only 2 left)
    // ph2
    READ_A(4, ofk0);
    FENCE; BAR; LGKM0; SB0;
    SP1; MFMA16(4); SP0;
    FENCE; BAR;
    // ph3  (acc[0-3] final after this)
    READ_B(ofk1); READ_A(0, ofk1);
    FENCE; BAR; LGKM0; SB0;
    SP1; MFMA16(0); SP0;
    // early store of acc[0-3] — overlaps ph4
    #pragma unroll
    for (int n = 0; n < 4; ++n) {
      const int col = nBase + wc * 64 + n * 16 + fr;
      const float bv = bias[col];
      #pragma unroll
      for (int m = 0; m < 4; ++m) {
        const int row0 = mBase + wr * 128 + m * 16 + fq * 4;
        #pragma unroll
        for (int r = 0; r < 4; ++r)
          C[(size_t)(row0 + r) * Nn + col] = acc[m][n][r] + bv;
      }
    }
    FENCE; BAR;
    // ph4
    READ_A(4, ofk1);
    FENCE; BAR; LGKM0; SB0;
    SP1; MFMA16(4); SP0;
  }

  // ---- remaining epilogue: acc[4-7] ----
  #pragma unroll
  for (int n = 0; n < 4; ++n) {
    const int col = nBase + wc * 64 + n * 16 + fr;
    const float bv = bias[col];
    #pragma unroll
    for (int m = 4; m < 8; ++m) {
      const int row0 = mBase + wr * 128 + m * 16 + fq * 4;
      #pragma unroll
      for (int r = 0; r < 4; ++r)
        C[(size_t)(row0 + r) * Nn + col] = acc[m][n][r] + bv;
    }
  }
}

extern "C" void kernel_launch(void* const* d_in, const int* in_sizes, int n_in,
                              void* d_out, int out_size, void* d_ws, size_t ws_size,
                              hipStream_t stream) {
  const float* x    = (const float*)d_in[0];
  const float* y    = (const float*)d_in[1];
  const float* W    = (const float*)d_in[2];
  const float* bias = (const float*)d_in[3];
  float* out = (float*)d_out;

  // Workspace: A (16384x1024 bf16 = 32 MB) + Wbf16 (2 MB)
  __hip_bfloat16* Abuf = (__hip_bfloat16*)d_ws;
  __hip_bfloat16* Wbuf = (__hip_bfloat16*)((char*)d_ws + (size_t)16384 * 1024 * 2);

  wcvt_kernel<<<1024, 256, 0, stream>>>(W, Wbuf);
  attn_kernel<<<4096, 256, 0, stream>>>(x, y, Abuf);
  gemm256<<<256, 512, 0, stream>>>(Abuf, Wbuf, bias, out);
}